// Round 1
// baseline (2373.352 us; speedup 1.0000x reference)
//
#include <hip/hip_runtime.h>

#define NNODES 50000
#define NEDGES 800000
#define NGRAPHS 1000
#define BN_EPS 1e-5f

// ---------------- elementwise helpers ----------------

__global__ void zero_f32(float* __restrict__ p, int n) {
    int i = blockIdx.x * blockDim.x + threadIdx.x;
    if (i < n) p[i] = 0.f;
}

__global__ void copy_f32(const float* __restrict__ a, float* __restrict__ b, int n) {
    int i = blockIdx.x * blockDim.x + threadIdx.x;
    if (i < n) b[i] = a[i];
}

// ---------------- GIN aggregation: agg[dst] += h[src] per edge ----------------

template <int F>
__global__ void scatter_add(const float* __restrict__ h, float* __restrict__ agg,
                            const int* __restrict__ src, const int* __restrict__ dst, int E) {
    int idx = blockIdx.x * blockDim.x + threadIdx.x;
    int e = idx / F;          // F is a compile-time constant -> magic-mul division
    int f = idx - e * F;
    if (e < E) {
        atomicAdd(&agg[dst[e] * F + f], h[src[e] * F + f]);
    }
}

// ---------------- pool: hg[batch[node]] += h[node], F=256 ----------------

__global__ void pool_scatter(const float* __restrict__ h, float* __restrict__ hg,
                             const int* __restrict__ batch, int n /* NNODES*256 */) {
    int idx = blockIdx.x * blockDim.x + threadIdx.x;
    if (idx < n) {
        int node = idx >> 8;
        int f = idx & 255;
        atomicAdd(&hg[batch[node] * 256 + f], h[idx]);
    }
}

// ---------------- fp32 GEMM: C[M,N] = A[M,K] @ W[K,N] + bias[N] ----------------
// 64x64 block tile, BK=16, 256 threads, 4x4 microtile per thread.

#define BM 64
#define BN 64
#define BK 16

__global__ __launch_bounds__(256) void gemm_bias(const float* __restrict__ A,
                                                 const float* __restrict__ W,
                                                 const float* __restrict__ bias,
                                                 float* __restrict__ C,
                                                 int M, int K, int N) {
    __shared__ float As[BK][BM + 1];
    __shared__ float Ws[BK][BN + 1];

    const int bm = blockIdx.y * BM;
    const int bn = blockIdx.x * BN;
    const int tid = threadIdx.x;
    const int tm = tid / 16;   // 0..15
    const int tn = tid % 16;   // 0..15

    float acc[4][4] = {};

    const int ac = tid % 16;   // k within tile
    const int ar = tid / 16;   // row base
    const int wn = tid % 64;   // n within tile
    const int wk = tid / 64;   // k base

    for (int k0 = 0; k0 < K; k0 += BK) {
        // load A tile: 64 rows x 16 k
        #pragma unroll
        for (int i = 0; i < 4; i++) {
            int row = bm + ar + i * 16;
            int kk = k0 + ac;
            As[ac][ar + i * 16] = (row < M && kk < K) ? A[row * K + kk] : 0.f;
        }
        // load W tile: 16 k x 64 n
        #pragma unroll
        for (int i = 0; i < 4; i++) {
            int kk = k0 + wk + i * 4;
            Ws[wk + i * 4][wn] = (kk < K) ? W[kk * N + bn + wn] : 0.f;
        }
        __syncthreads();

        #pragma unroll
        for (int k = 0; k < BK; k++) {
            float a[4], w[4];
            #pragma unroll
            for (int i = 0; i < 4; i++) a[i] = As[k][tm * 4 + i];
            #pragma unroll
            for (int j = 0; j < 4; j++) w[j] = Ws[k][tn * 4 + j];
            #pragma unroll
            for (int i = 0; i < 4; i++)
                #pragma unroll
                for (int j = 0; j < 4; j++) acc[i][j] += a[i] * w[j];
        }
        __syncthreads();
    }

    #pragma unroll
    for (int i = 0; i < 4; i++) {
        int row = bm + tm * 4 + i;
        if (row < M) {
            #pragma unroll
            for (int j = 0; j < 4; j++) {
                int col = bn + tn * 4 + j;
                C[row * N + col] = acc[i][j] + bias[col];
            }
        }
    }
}

// ---------------- BatchNorm (training-mode, biased var) ----------------

__global__ void bn_stats(const float* __restrict__ z, float* __restrict__ sums,
                         float* __restrict__ sumsq, int M, int F, int rpb) {
    int f = threadIdx.x;            // blockDim.x == F
    int r0 = blockIdx.x * rpb;
    int rend = min(r0 + rpb, M);
    float s = 0.f, q = 0.f;
    for (int r = r0; r < rend; r++) {
        float v = z[r * F + f];
        s += v;
        q += v * v;
    }
    atomicAdd(&sums[f], s);
    atomicAdd(&sumsq[f], q);
}

__global__ void bn_finalize(const float* __restrict__ sums, const float* __restrict__ sumsq,
                            const float* __restrict__ g, const float* __restrict__ be,
                            float* __restrict__ s, float* __restrict__ t, int F, float invM) {
    int f = threadIdx.x;
    if (f < F) {
        float m = sums[f] * invM;
        float v = sumsq[f] * invM - m * m;
        float sc = g[f] * rsqrtf(v + BN_EPS);
        s[f] = sc;
        t[f] = be[f] - m * sc;
    }
}

__global__ void bn_apply_relu(float* __restrict__ z, const float* __restrict__ s,
                              const float* __restrict__ t, int n, int fmask) {
    int i = blockIdx.x * blockDim.x + threadIdx.x;
    if (i < n) {
        int f = i & fmask;   // F is 128 or 256 (power of 2)
        z[i] = fmaxf(0.f, z[i] * s[f] + t[f]);
    }
}

// ---------------- final head GEMV: out[g] = dot(hg2[g,:128], fw2) + fb2 ----------------

__global__ void final_gemv(const float* __restrict__ hg2, const float* __restrict__ fw2,
                           const float* __restrict__ fb2, float* __restrict__ out) {
    int g = blockIdx.x;
    int lane = threadIdx.x;  // 64
    float v = hg2[g * 128 + lane] * fw2[lane] + hg2[g * 128 + 64 + lane] * fw2[64 + lane];
    #pragma unroll
    for (int o = 32; o > 0; o >>= 1) v += __shfl_down(v, o);
    if (lane == 0) out[g] = v + fb2[0];
}

// ---------------- launch ----------------

extern "C" void kernel_launch(void* const* d_in, const int* in_sizes, int n_in,
                              void* d_out, int out_size, void* d_ws, size_t ws_size,
                              hipStream_t stream) {
    const float* x     = (const float*)d_in[0];
    const int*   ei    = (const int*)d_in[1];
    const int*   batch = (const int*)d_in[2];
    const int* esrc = ei;
    const int* edst = ei + NEDGES;

    const float* l1w = (const float*)d_in[3],  *l1b = (const float*)d_in[4],
               * l1g = (const float*)d_in[5],  *l1be = (const float*)d_in[6];
    const float* l2w = (const float*)d_in[7],  *l2b = (const float*)d_in[8],
               * l2g = (const float*)d_in[9],  *l2be = (const float*)d_in[10];
    const float* l3w = (const float*)d_in[11], *l3b = (const float*)d_in[12],
               * l3g = (const float*)d_in[13], *l3be = (const float*)d_in[14];
    const float* l4w = (const float*)d_in[15], *l4b = (const float*)d_in[16],
               * l4g = (const float*)d_in[17], *l4be = (const float*)d_in[18];
    const float* l5w = (const float*)d_in[19], *l5b = (const float*)d_in[20],
               * l5g = (const float*)d_in[21], *l5be = (const float*)d_in[22];
    const float* l6w = (const float*)d_in[23], *l6b = (const float*)d_in[24],
               * l6g = (const float*)d_in[25], *l6be = (const float*)d_in[26];
    const float* fw1 = (const float*)d_in[27], *fb1 = (const float*)d_in[28],
               * fg  = (const float*)d_in[29], *fbe = (const float*)d_in[30];
    const float* fw2 = (const float*)d_in[31], *fb2 = (const float*)d_in[32];

    float* ws = (float*)d_ws;
    float* buf0 = ws;
    float* buf1 = buf0 + (size_t)NNODES * 256;
    float* hg   = buf1 + (size_t)NNODES * 256;       // [1000, 256]
    float* hg2  = hg + NGRAPHS * 256;                // [1000, 128]
    float* stats = hg2 + NGRAPHS * 128;              // 7 BNs x 1024 floats

    // zero: hg + hg2 + stats (contiguous)
    {
        int zn = NGRAPHS * 256 + NGRAPHS * 128 + 7 * 1024;
        zero_f32<<<(zn + 255) / 256, 256, 0, stream>>>(hg, zn);
    }

    auto launch_gemm = [&](const float* A, const float* W, const float* b, float* C,
                           int M, int K, int N) {
        dim3 grid(N / BN, (M + BM - 1) / BM);
        gemm_bias<<<grid, 256, 0, stream>>>(A, W, b, C, M, K, N);
    };
    auto launch_bn = [&](float* z, int M, int F, const float* g, const float* be, float* st) {
        float* sums = st;
        float* sumsq = st + 256;
        float* s = st + 512;
        float* t = st + 768;
        int rpb = 128;
        bn_stats<<<(M + rpb - 1) / rpb, F, 0, stream>>>(z, sums, sumsq, M, F, rpb);
        bn_finalize<<<1, F, 0, stream>>>(sums, sumsq, g, be, s, t, F, 1.0f / (float)M);
        int n = M * F;
        bn_apply_relu<<<(n + 255) / 256, 256, 0, stream>>>(z, s, t, n, F - 1);
    };

    // ---- conv1: agg(x) [F=11] -> MLP(11->128->128) ----
    copy_f32<<<(NNODES * 11 + 255) / 256, 256, 0, stream>>>(x, buf0, NNODES * 11);
    scatter_add<11><<<((NEDGES * 11) + 255) / 256, 256, 0, stream>>>(x, buf0, esrc, edst, NEDGES);
    launch_gemm(buf0, l1w, l1b, buf1, NNODES, 11, 128);
    launch_bn(buf1, NNODES, 128, l1g, l1be, stats + 0 * 1024);
    launch_gemm(buf1, l2w, l2b, buf0, NNODES, 128, 128);
    launch_bn(buf0, NNODES, 128, l2g, l2be, stats + 1 * 1024);

    // ---- conv2: agg [F=128] -> MLP(128->256->256) ----
    copy_f32<<<(NNODES * 128 + 255) / 256, 256, 0, stream>>>(buf0, buf1, NNODES * 128);
    scatter_add<128><<<((NEDGES * 128) + 255) / 256, 256, 0, stream>>>(buf0, buf1, esrc, edst, NEDGES);
    launch_gemm(buf1, l3w, l3b, buf0, NNODES, 128, 256);
    launch_bn(buf0, NNODES, 256, l3g, l3be, stats + 2 * 1024);
    launch_gemm(buf0, l4w, l4b, buf1, NNODES, 256, 256);
    launch_bn(buf1, NNODES, 256, l4g, l4be, stats + 3 * 1024);

    // ---- conv3: agg [F=256] -> MLP(256->256->256) ----
    copy_f32<<<(NNODES * 256 + 255) / 256, 256, 0, stream>>>(buf1, buf0, NNODES * 256);
    scatter_add<256><<<((NEDGES * 256) + 255) / 256, 256, 0, stream>>>(buf1, buf0, esrc, edst, NEDGES);
    launch_gemm(buf0, l5w, l5b, buf1, NNODES, 256, 256);
    launch_bn(buf1, NNODES, 256, l5g, l5be, stats + 4 * 1024);
    launch_gemm(buf1, l6w, l6b, buf0, NNODES, 256, 256);
    launch_bn(buf0, NNODES, 256, l6g, l6be, stats + 5 * 1024);

    // ---- pool + head ----
    pool_scatter<<<(NNODES * 256 + 255) / 256, 256, 0, stream>>>(buf0, hg, batch, NNODES * 256);
    launch_gemm(hg, fw1, fb1, hg2, NGRAPHS, 256, 128);
    launch_bn(hg2, NGRAPHS, 128, fg, fbe, stats + 6 * 1024);
    final_gemv<<<NGRAPHS, 64, 0, stream>>>(hg2, fw2, fb2, (float*)d_out);
}

// Round 2
// 1010.585 us; speedup vs baseline: 2.3485x; 2.3485x over previous
//
#include <hip/hip_runtime.h>

#define NNODES 50000
#define NEDGES 800000
#define NGRAPHS 1000
#define BN_EPS 1e-5f

// ================= elementwise =================

__global__ void zero_f32(float* __restrict__ p, int n) {
    int i = blockIdx.x * blockDim.x + threadIdx.x;
    if (i < n) p[i] = 0.f;
}

// ================= CSR build =================

__global__ void csr_hist(const int* __restrict__ dst, int* __restrict__ deg, int E) {
    int e = blockIdx.x * blockDim.x + threadIdx.x;
    if (e < E) atomicAdd(&deg[dst[e]], 1);
}

// inclusive scan of 1024-chunks
__global__ void csr_scan1(const int* __restrict__ deg, int* __restrict__ tmpscan,
                          int* __restrict__ chunkTot, int n) {
    __shared__ int sm[1024];
    int i = blockIdx.x * 1024 + threadIdx.x;
    int v = (i < n) ? deg[i] : 0;
    sm[threadIdx.x] = v;
    __syncthreads();
    for (int off = 1; off < 1024; off <<= 1) {
        int add = (threadIdx.x >= off) ? sm[threadIdx.x - off] : 0;
        __syncthreads();
        sm[threadIdx.x] += add;
        __syncthreads();
    }
    if (i < n) tmpscan[i] = sm[threadIdx.x];
    if (threadIdx.x == 1023) chunkTot[blockIdx.x] = sm[1023];
}

__global__ void csr_scan2(int* __restrict__ chunkTot, int nchunks) {
    if (threadIdx.x == 0 && blockIdx.x == 0) {
        int run = 0;
        for (int c = 0; c < nchunks; c++) {
            int t = chunkTot[c];
            chunkTot[c] = run;
            run += t;
        }
    }
}

__global__ void csr_scan3(const int* __restrict__ deg, const int* __restrict__ tmpscan,
                          const int* __restrict__ chunkTot, int* __restrict__ rowptr,
                          int* __restrict__ cursor, int n) {
    int i = blockIdx.x * blockDim.x + threadIdx.x;
    if (i < n) {
        int inc = tmpscan[i] + chunkTot[i >> 10];
        rowptr[i + 1] = inc;
        cursor[i] = inc - deg[i];
        if (i == 0) rowptr[0] = 0;
    }
}

__global__ void csr_fill(const int* __restrict__ src, const int* __restrict__ dst,
                         int* __restrict__ cursor, int* __restrict__ eidx, int E) {
    int e = blockIdx.x * blockDim.x + threadIdx.x;
    if (e < E) {
        int pos = atomicAdd(&cursor[dst[e]], 1);
        eidx[pos] = src[e];
    }
}

// ================= GIN gather aggregation =================
// out[n] = h(n) + sum_{e: dst=n} h(src(e)),  h = BN? relu(z*s+t) : z

template <int F, bool BN>
__global__ void gin_gather(const float* __restrict__ z, const float* __restrict__ s,
                           const float* __restrict__ t, const int* __restrict__ rowptr,
                           const int* __restrict__ eidx, float* __restrict__ out) {
    int n = blockIdx.x;
    int f = threadIdx.x;  // blockDim.x == F
    float sv = BN ? s[f] : 0.f;
    float tv = BN ? t[f] : 0.f;
    float v = z[n * F + f];
    float acc = BN ? fmaxf(0.f, v * sv + tv) : v;
    int p0 = rowptr[n], p1 = rowptr[n + 1];
    for (int p = p0; p < p1; p++) {
        int src = eidx[p];
        float u = z[src * F + f];
        acc += BN ? fmaxf(0.f, u * sv + tv) : u;
    }
    out[n * F + f] = acc;
}

// F=11 version: 16 threads per node
__global__ void gin_gather11(const float* __restrict__ x, const int* __restrict__ rowptr,
                             const int* __restrict__ eidx, float* __restrict__ out) {
    int local = threadIdx.x >> 4;
    int lane = threadIdx.x & 15;
    int n = blockIdx.x * 16 + local;
    if (n >= NNODES) return;
    int p0 = rowptr[n], p1 = rowptr[n + 1];
    float acc = (lane < 11) ? x[n * 11 + lane] : 0.f;
    for (int p = p0; p < p1; p++) {
        int src = eidx[p];
        if (lane < 11) acc += x[src * 11 + lane];
    }
    if (lane < 11) out[n * 11 + lane] = acc;
}

// ================= fused GEMM =================
// C[M,N] = A'[M,K] @ W[K,N] + bias ;  A' = BN_A ? relu(A*sA+tA) : A  (sA,tA over K)
// Also accumulates column sums/sumsq of C into global stats (for the following BN).
// 128x128 tile, BK=16, 256 threads, 8x8 microtile as 2x2 blocks of 4x4.

#define GBM 128
#define GBN 128
#define GBK 16
#define LDA 132  // padded row length (floats), 528B = 16B-aligned

template <bool BN_A>
__global__ __launch_bounds__(256) void gemm_fused(
    const float* __restrict__ A, const float* __restrict__ W, const float* __restrict__ bias,
    const float* __restrict__ sA, const float* __restrict__ tA,
    float* __restrict__ C, float* __restrict__ sums, float* __restrict__ sumsq,
    int M, int K, int N) {
    __shared__ float smem[2 * GBK * LDA];  // 4224 floats = 16.9 KB
    float* As = smem;                       // [GBK][LDA]
    float* Ws = smem + GBK * LDA;           // [GBK][LDA]

    const int bm = blockIdx.y * GBM;
    const int bn = blockIdx.x * GBN;
    const int tid = threadIdx.x;
    const int tm = tid >> 4;   // 0..15
    const int tn = tid & 15;   // 0..15

    float acc[2][2][4][4] = {};

    const bool k_aligned = (K & 3) == 0;

    for (int k0 = 0; k0 < K; k0 += GBK) {
        // ---- load A tile: 128 rows x 16 k  (512 float4, 2 per thread) ----
        #pragma unroll
        for (int i = 0; i < 2; i++) {
            int id = tid + 256 * i;
            int row = id >> 2;       // 0..127
            int kq = id & 3;         // 0..3
            int gr = bm + row;
            int kk = k0 + kq * 4;
            float4 a4 = make_float4(0.f, 0.f, 0.f, 0.f);
            if (gr < M) {
                if (k_aligned) {
                    if (kk < K) {
                        a4 = *(const float4*)&A[(size_t)gr * K + kk];
                        if (BN_A) {
                            float4 s4 = *(const float4*)&sA[kk];
                            float4 t4 = *(const float4*)&tA[kk];
                            a4.x = fmaxf(0.f, a4.x * s4.x + t4.x);
                            a4.y = fmaxf(0.f, a4.y * s4.y + t4.y);
                            a4.z = fmaxf(0.f, a4.z * s4.z + t4.z);
                            a4.w = fmaxf(0.f, a4.w * s4.w + t4.w);
                        }
                    }
                } else {
                    float tmp[4];
                    #pragma unroll
                    for (int j = 0; j < 4; j++) {
                        int kj = kk + j;
                        float v = (kj < K) ? A[(size_t)gr * K + kj] : 0.f;
                        if (BN_A && kj < K) v = fmaxf(0.f, v * sA[kj] + tA[kj]);
                        tmp[j] = v;
                    }
                    a4 = make_float4(tmp[0], tmp[1], tmp[2], tmp[3]);
                }
            }
            As[(kq * 4 + 0) * LDA + row] = a4.x;
            As[(kq * 4 + 1) * LDA + row] = a4.y;
            As[(kq * 4 + 2) * LDA + row] = a4.z;
            As[(kq * 4 + 3) * LDA + row] = a4.w;
        }
        // ---- load W tile: 16 k x 128 n (512 float4, 2 per thread) ----
        #pragma unroll
        for (int i = 0; i < 2; i++) {
            int id = tid + 256 * i;
            int kl = id >> 5;        // 0..15
            int c = id & 31;         // 0..31
            int kk = k0 + kl;
            float4 w4 = make_float4(0.f, 0.f, 0.f, 0.f);
            if (kk < K) w4 = *(const float4*)&W[(size_t)kk * N + bn + c * 4];
            *(float4*)&Ws[kl * LDA + c * 4] = w4;
        }
        __syncthreads();

        // ---- inner product ----
        #pragma unroll
        for (int k = 0; k < GBK; k++) {
            float4 a0 = *(float4*)&As[k * LDA + tm * 4];
            float4 a1 = *(float4*)&As[k * LDA + 64 + tm * 4];
            float4 w0 = *(float4*)&Ws[k * LDA + tn * 4];
            float4 w1 = *(float4*)&Ws[k * LDA + 64 + tn * 4];
            float ar[2][4] = {{a0.x, a0.y, a0.z, a0.w}, {a1.x, a1.y, a1.z, a1.w}};
            float wr[2][4] = {{w0.x, w0.y, w0.z, w0.w}, {w1.x, w1.y, w1.z, w1.w}};
            #pragma unroll
            for (int ri = 0; ri < 2; ri++)
                #pragma unroll
                for (int ci = 0; ci < 2; ci++)
                    #pragma unroll
                    for (int ii = 0; ii < 4; ii++)
                        #pragma unroll
                        for (int jj = 0; jj < 4; jj++)
                            acc[ri][ci][ii][jj] += ar[ri][ii] * wr[ci][jj];
        }
        __syncthreads();
    }

    // ---- epilogue: bias, write C, column stats ----
    float colsum[2][4] = {};   // [ci][j]
    float colsq[2][4] = {};

    #pragma unroll
    for (int ci = 0; ci < 2; ci++) {
        float4 b4 = *(const float4*)&bias[bn + ci * 64 + tn * 4];
        float br[4] = {b4.x, b4.y, b4.z, b4.w};
        #pragma unroll
        for (int ri = 0; ri < 2; ri++) {
            #pragma unroll
            for (int ii = 0; ii < 4; ii++) {
                int row = bm + ri * 64 + tm * 4 + ii;
                if (row < M) {
                    float z0 = acc[ri][ci][ii][0] + br[0];
                    float z1 = acc[ri][ci][ii][1] + br[1];
                    float z2 = acc[ri][ci][ii][2] + br[2];
                    float z3 = acc[ri][ci][ii][3] + br[3];
                    *(float4*)&C[(size_t)row * N + bn + ci * 64 + tn * 4] =
                        make_float4(z0, z1, z2, z3);
                    colsum[ci][0] += z0; colsq[ci][0] += z0 * z0;
                    colsum[ci][1] += z1; colsq[ci][1] += z1 * z1;
                    colsum[ci][2] += z2; colsq[ci][2] += z2 * z2;
                    colsum[ci][3] += z3; colsq[ci][3] += z3 * z3;
                }
            }
        }
    }

    // reduce partials across tm via LDS (reuse smem)
    __syncthreads();
    float* ps = smem;          // [16][128]
    float* pq = smem + 2048;   // [16][128]
    #pragma unroll
    for (int ci = 0; ci < 2; ci++)
        #pragma unroll
        for (int jj = 0; jj < 4; jj++) {
            int cl = ci * 64 + tn * 4 + jj;
            ps[tm * 128 + cl] = colsum[ci][jj];
            pq[tm * 128 + cl] = colsq[ci][jj];
        }
    __syncthreads();
    if (tid < 128) {
        float s = 0.f, q = 0.f;
        #pragma unroll
        for (int i = 0; i < 16; i++) {
            s += ps[i * 128 + tid];
            q += pq[i * 128 + tid];
        }
        atomicAdd(&sums[bn + tid], s);
        atomicAdd(&sumsq[bn + tid], q);
    }
}

// ================= BN finalize =================

__global__ void bn_finalize(const float* __restrict__ sums, const float* __restrict__ sumsq,
                            const float* __restrict__ g, const float* __restrict__ be,
                            float* __restrict__ s, float* __restrict__ t, int F, float invM) {
    int f = threadIdx.x;
    if (f < F) {
        float m = sums[f] * invM;
        float v = sumsq[f] * invM - m * m;
        float sc = g[f] * rsqrtf(v + BN_EPS);
        s[f] = sc;
        t[f] = be[f] - m * sc;
    }
}

// ================= pool (BN+relu fused, chunked flush) =================

__global__ void pool_bn(const float* __restrict__ z, const float* __restrict__ s,
                        const float* __restrict__ t, const int* __restrict__ batch,
                        float* __restrict__ hg) {
    int f = threadIdx.x;  // 256
    int n0 = blockIdx.x * 32;
    int n1 = min(n0 + 32, NNODES);
    float sv = s[f], tv = t[f];
    float acc = 0.f;
    int gc = batch[n0];
    for (int n = n0; n < n1; n++) {
        int g = batch[n];
        if (g != gc) {
            atomicAdd(&hg[gc * 256 + f], acc);
            acc = 0.f;
            gc = g;
        }
        float v = z[(size_t)n * 256 + f];
        acc += fmaxf(0.f, v * sv + tv);
    }
    atomicAdd(&hg[gc * 256 + f], acc);
}

// ================= final head GEMV (BN+relu fused) =================

__global__ void final_gemv(const float* __restrict__ hg2, const float* __restrict__ s,
                           const float* __restrict__ t, const float* __restrict__ fw2,
                           const float* __restrict__ fb2, float* __restrict__ out) {
    int g = blockIdx.x;
    int l = threadIdx.x;  // 64
    float a0 = fmaxf(0.f, hg2[g * 128 + l] * s[l] + t[l]) * fw2[l];
    float a1 = fmaxf(0.f, hg2[g * 128 + 64 + l] * s[64 + l] + t[64 + l]) * fw2[64 + l];
    float v = a0 + a1;
    #pragma unroll
    for (int o = 32; o > 0; o >>= 1) v += __shfl_down(v, o);
    if (l == 0) out[g] = v + fb2[0];
}

// ================= launch =================

extern "C" void kernel_launch(void* const* d_in, const int* in_sizes, int n_in,
                              void* d_out, int out_size, void* d_ws, size_t ws_size,
                              hipStream_t stream) {
    const float* x = (const float*)d_in[0];
    const int* ei = (const int*)d_in[1];
    const int* batch = (const int*)d_in[2];
    const int* esrc = ei;
    const int* edst = ei + NEDGES;

    const float* l1w = (const float*)d_in[3],  *l1b = (const float*)d_in[4],
               * l1g = (const float*)d_in[5],  *l1be = (const float*)d_in[6];
    const float* l2w = (const float*)d_in[7],  *l2b = (const float*)d_in[8],
               * l2g = (const float*)d_in[9],  *l2be = (const float*)d_in[10];
    const float* l3w = (const float*)d_in[11], *l3b = (const float*)d_in[12],
               * l3g = (const float*)d_in[13], *l3be = (const float*)d_in[14];
    const float* l4w = (const float*)d_in[15], *l4b = (const float*)d_in[16],
               * l4g = (const float*)d_in[17], *l4be = (const float*)d_in[18];
    const float* l5w = (const float*)d_in[19], *l5b = (const float*)d_in[20],
               * l5g = (const float*)d_in[21], *l5be = (const float*)d_in[22];
    const float* l6w = (const float*)d_in[23], *l6b = (const float*)d_in[24],
               * l6g = (const float*)d_in[25], *l6be = (const float*)d_in[26];
    const float* fw1 = (const float*)d_in[27], *fb1 = (const float*)d_in[28],
               * fg  = (const float*)d_in[29], *fbe = (const float*)d_in[30];
    const float* fw2 = (const float*)d_in[31], *fb2 = (const float*)d_in[32];

    // ---- workspace layout (floats / ints) ----
    float* buf0 = (float*)d_ws;
    float* buf1 = buf0 + (size_t)NNODES * 256;
    float* hg   = buf1 + (size_t)NNODES * 256;        // [1000,256]
    float* hg2  = hg + NGRAPHS * 256;                 // [1000,128]
    float* stats = hg2 + NGRAPHS * 128;               // 7 x 1024
    int* deg     = (int*)(stats + 7 * 1024);          // [50001]
    int* rowptr  = deg + (NNODES + 1);                // [50001]
    int* cursor  = rowptr + (NNODES + 1);             // [50001]
    int* chunkTot = cursor + (NNODES + 1);            // [64]
    int* tmpscan = chunkTot + 64;                     // [50001]
    int* eidx    = tmpscan + (NNODES + 1);            // [800000]

    // zero: hg + hg2 + stats + deg (contiguous)
    {
        int zn = NGRAPHS * 256 + NGRAPHS * 128 + 7 * 1024 + (NNODES + 1);
        zero_f32<<<(zn + 255) / 256, 256, 0, stream>>>(hg, zn);
    }

    // ---- CSR build ----
    csr_hist<<<(NEDGES + 255) / 256, 256, 0, stream>>>(edst, deg, NEDGES);
    int nchunks = (NNODES + 1023) / 1024;  // 49
    csr_scan1<<<nchunks, 1024, 0, stream>>>(deg, tmpscan, chunkTot, NNODES);
    csr_scan2<<<1, 64, 0, stream>>>(chunkTot, nchunks);
    csr_scan3<<<(NNODES + 255) / 256, 256, 0, stream>>>(deg, tmpscan, chunkTot, rowptr,
                                                        cursor, NNODES);
    csr_fill<<<(NEDGES + 255) / 256, 256, 0, stream>>>(esrc, edst, cursor, eidx, NEDGES);

    auto st = [&](int i) { return stats + i * 1024; };
    auto gemm = [&](bool bnA, const float* A, const float* W, const float* b,
                    const float* sA, const float* tA, float* C, float* sums, float* sq,
                    int M, int K, int N) {
        dim3 grid((N + GBN - 1) / GBN, (M + GBM - 1) / GBM);
        if (bnA)
            gemm_fused<true><<<grid, 256, 0, stream>>>(A, W, b, sA, tA, C, sums, sq, M, K, N);
        else
            gemm_fused<false><<<grid, 256, 0, stream>>>(A, W, b, sA, tA, C, sums, sq, M, K, N);
    };
    auto fin = [&](int i, const float* g, const float* be, int F, float invM) {
        bn_finalize<<<1, 256, 0, stream>>>(st(i), st(i) + 256, g, be, st(i) + 512,
                                           st(i) + 768, F, invM);
    };
    const float invN = 1.0f / (float)NNODES;
    const float invG = 1.0f / (float)NGRAPHS;

    // ---- conv1: agg(x) [F=11] -> MLP(11->128->128) ----
    gin_gather11<<<(NNODES + 15) / 16, 256, 0, stream>>>(x, rowptr, eidx, buf0);
    gemm(false, buf0, l1w, l1b, nullptr, nullptr, buf1, st(0), st(0) + 256, NNODES, 11, 128);
    fin(0, l1g, l1be, 128, invN);
    gemm(true, buf1, l2w, l2b, st(0) + 512, st(0) + 768, buf0, st(1), st(1) + 256,
         NNODES, 128, 128);
    fin(1, l2g, l2be, 128, invN);

    // ---- conv2: agg(bnrelu(z2)) [F=128] -> MLP(128->256->256) ----
    gin_gather<128, true><<<NNODES, 128, 0, stream>>>(buf0, st(1) + 512, st(1) + 768,
                                                      rowptr, eidx, buf1);
    gemm(false, buf1, l3w, l3b, nullptr, nullptr, buf0, st(2), st(2) + 256, NNODES, 128, 256);
    fin(2, l3g, l3be, 256, invN);
    gemm(true, buf0, l4w, l4b, st(2) + 512, st(2) + 768, buf1, st(3), st(3) + 256,
         NNODES, 256, 256);
    fin(3, l4g, l4be, 256, invN);

    // ---- conv3: agg(bnrelu(z4)) [F=256] -> MLP(256->256->256) ----
    gin_gather<256, true><<<NNODES, 256, 0, stream>>>(buf1, st(3) + 512, st(3) + 768,
                                                      rowptr, eidx, buf0);
    gemm(false, buf0, l5w, l5b, nullptr, nullptr, buf1, st(4), st(4) + 256, NNODES, 256, 256);
    fin(4, l5g, l5be, 256, invN);
    gemm(true, buf1, l6w, l6b, st(4) + 512, st(4) + 768, buf0, st(5), st(5) + 256,
         NNODES, 256, 256);
    fin(5, l6g, l6be, 256, invN);

    // ---- pool + head ----
    pool_bn<<<(NNODES + 31) / 32, 256, 0, stream>>>(buf0, st(5) + 512, st(5) + 768, batch, hg);
    gemm(false, hg, fw1, fb1, nullptr, nullptr, hg2, st(6), st(6) + 256, NGRAPHS, 256, 128);
    fin(6, fg, fbe, 128, invG);
    final_gemv<<<NGRAPHS, 64, 0, stream>>>(hg2, st(6) + 512, st(6) + 768, fw2, fb2,
                                           (float*)d_out);
}

// Round 3
// 762.766 us; speedup vs baseline: 3.1115x; 1.3249x over previous
//
#include <hip/hip_runtime.h>

#define NNODES 50000
#define NEDGES 800000
#define NGRAPHS 1000
#define BN_EPS 1e-5f
#define MPAD 50048   // 391 * 128

typedef unsigned short us_t;
typedef us_t us8 __attribute__((ext_vector_type(8)));
typedef us_t us4 __attribute__((ext_vector_type(4)));
typedef __bf16 bf16x8 __attribute__((ext_vector_type(8)));
typedef float f32x4 __attribute__((ext_vector_type(4)));

__device__ __forceinline__ float b2f(us_t u) {
    union { unsigned int i; float f; } v;
    v.i = ((unsigned int)u) << 16;
    return v.f;
}
__device__ __forceinline__ us_t f2b(float x) {
    unsigned int u = __float_as_uint(x);
    unsigned int r = u + 0x7FFFu + ((u >> 16) & 1u);
    return (us_t)(r >> 16);
}
__device__ __forceinline__ bf16x8 as_bf(us8 v) {
    union { us8 u; bf16x8 b; } c;
    c.u = v;
    return c.b;
}

// ================= elementwise =================

__global__ void zero_f32(float* __restrict__ p, int n) {
    int i = blockIdx.x * blockDim.x + threadIdx.x;
    if (i < n) p[i] = 0.f;
}

// ================= CSR build =================

__global__ void csr_hist(const int* __restrict__ dst, int* __restrict__ deg, int E) {
    int e = blockIdx.x * blockDim.x + threadIdx.x;
    if (e < E) atomicAdd(&deg[dst[e]], 1);
}

__global__ void csr_scan1(const int* __restrict__ deg, int* __restrict__ tmpscan,
                          int* __restrict__ chunkTot, int n) {
    __shared__ int sm[1024];
    int i = blockIdx.x * 1024 + threadIdx.x;
    int v = (i < n) ? deg[i] : 0;
    sm[threadIdx.x] = v;
    __syncthreads();
    for (int off = 1; off < 1024; off <<= 1) {
        int add = (threadIdx.x >= off) ? sm[threadIdx.x - off] : 0;
        __syncthreads();
        sm[threadIdx.x] += add;
        __syncthreads();
    }
    if (i < n) tmpscan[i] = sm[threadIdx.x];
    if (threadIdx.x == 1023) chunkTot[blockIdx.x] = sm[1023];
}

__global__ void csr_scan2(int* __restrict__ chunkTot, int nchunks) {
    if (threadIdx.x == 0 && blockIdx.x == 0) {
        int run = 0;
        for (int c = 0; c < nchunks; c++) {
            int t = chunkTot[c];
            chunkTot[c] = run;
            run += t;
        }
    }
}

__global__ void csr_scan3(const int* __restrict__ deg, const int* __restrict__ tmpscan,
                          const int* __restrict__ chunkTot, int* __restrict__ rowptr,
                          int* __restrict__ cursor, int n) {
    int i = blockIdx.x * blockDim.x + threadIdx.x;
    if (i < n) {
        int inc = tmpscan[i] + chunkTot[i >> 10];
        rowptr[i + 1] = inc;
        cursor[i] = inc - deg[i];
        if (i == 0) rowptr[0] = 0;
    }
}

__global__ void csr_fill(const int* __restrict__ src, const int* __restrict__ dst,
                         int* __restrict__ cursor, int* __restrict__ eidx, int E) {
    int e = blockIdx.x * blockDim.x + threadIdx.x;
    if (e < E) {
        int pos = atomicAdd(&cursor[dst[e]], 1);
        eidx[pos] = src[e];
    }
}

// ================= weight convert: W[K][N] fp32 -> Wt[N][K] bf16 =================

__global__ void wt_convert(const float* __restrict__ W, us_t* __restrict__ Wt, int K, int N) {
    int i = blockIdx.x * blockDim.x + threadIdx.x;
    if (i < K * N) {
        int k = i / N;
        int n = i - k * N;
        Wt[n * K + k] = f2b(W[i]);
    }
}

// ================= GIN gather (bf16, fused BN+relu) =================
// out[n] = h(n) + sum_{j->n} h(j),  h = relu(z*s + t)

template <int F>
__global__ void gin_gather_bf(const us_t* __restrict__ z, const float* __restrict__ s,
                              const float* __restrict__ t, const int* __restrict__ rowptr,
                              const int* __restrict__ eidx, us_t* __restrict__ out) {
    constexpr int TPN = F / 4;          // threads per node
    constexpr int NPB = 256 / TPN;      // nodes per block
    int ln = threadIdx.x / TPN;
    int fp = threadIdx.x % TPN;
    int n = blockIdx.x * NPB + ln;
    if (n >= NNODES) return;
    int f0 = fp * 4;
    float4 sv = *(const float4*)&s[f0];
    float4 tv = *(const float4*)&t[f0];

    us4 v = *(const us4*)&z[(size_t)n * F + f0];
    float a0 = fmaxf(0.f, b2f(v[0]) * sv.x + tv.x);
    float a1 = fmaxf(0.f, b2f(v[1]) * sv.y + tv.y);
    float a2 = fmaxf(0.f, b2f(v[2]) * sv.z + tv.z);
    float a3 = fmaxf(0.f, b2f(v[3]) * sv.w + tv.w);

    int p0 = rowptr[n], p1 = rowptr[n + 1];
    for (int p = p0; p < p1; p++) {
        int src = eidx[p];
        us4 u = *(const us4*)&z[(size_t)src * F + f0];
        a0 += fmaxf(0.f, b2f(u[0]) * sv.x + tv.x);
        a1 += fmaxf(0.f, b2f(u[1]) * sv.y + tv.y);
        a2 += fmaxf(0.f, b2f(u[2]) * sv.z + tv.z);
        a3 += fmaxf(0.f, b2f(u[3]) * sv.w + tv.w);
    }
    us4 o;
    o[0] = f2b(a0); o[1] = f2b(a1); o[2] = f2b(a2); o[3] = f2b(a3);
    *(us4*)&out[(size_t)n * F + f0] = o;
}

// F=11 fp32 gather (input features)
__global__ void gin_gather11(const float* __restrict__ x, const int* __restrict__ rowptr,
                             const int* __restrict__ eidx, float* __restrict__ out) {
    int local = threadIdx.x >> 4;
    int lane = threadIdx.x & 15;
    int n = blockIdx.x * 16 + local;
    if (n >= NNODES) return;
    int p0 = rowptr[n], p1 = rowptr[n + 1];
    float acc = (lane < 11) ? x[n * 11 + lane] : 0.f;
    for (int p = p0; p < p1; p++) {
        int src = eidx[p];
        if (lane < 11) acc += x[src * 11 + lane];
    }
    if (lane < 11) out[n * 11 + lane] = acc;
}

// ================= layer-1 GEMM: [M,11] fp32 @ [11,128] + b -> bf16 + stats =================

__global__ __launch_bounds__(256) void gemm11(const float* __restrict__ A,
                                              const float* __restrict__ W,
                                              const float* __restrict__ b,
                                              us_t* __restrict__ C,
                                              float* __restrict__ sums,
                                              float* __restrict__ sumsq) {
    __shared__ float sW[11 * 128];
    __shared__ float sArows[64 * 11];
    int tid = threadIdx.x;
    for (int i = tid; i < 11 * 128; i += 256) sW[i] = W[i];
    int r0 = blockIdx.x * 64;
    for (int i = tid; i < 64 * 11; i += 256) {
        int r = i / 11, c = i - r * 11;
        sArows[i] = (r0 + r < NNODES) ? A[(r0 + r) * 11 + c] : 0.f;
    }
    __syncthreads();
    int col = tid & 127;
    int half = tid >> 7;
    float bias = b[col];
    float cs = 0.f, cq = 0.f;
    for (int rr = half * 32; rr < half * 32 + 32; rr++) {
        int row = r0 + rr;
        if (row < NNODES) {
            float acc = bias;
            #pragma unroll
            for (int k = 0; k < 11; k++) acc += sArows[rr * 11 + k] * sW[k * 128 + col];
            C[(size_t)row * 128 + col] = f2b(acc);
            cs += acc;
            cq += acc * acc;
        }
    }
    __syncthreads();
    sArows[tid] = cs;
    sArows[256 + tid] = cq;
    __syncthreads();
    if (tid < 128) {
        atomicAdd(&sums[tid], sArows[tid] + sArows[tid + 128]);
        atomicAdd(&sumsq[tid], sArows[256 + tid] + sArows[256 + tid + 128]);
    }
}

// ================= MFMA GEMM: C[M,N] = A[M,K]bf16 @ Wt[N,K]bf16^T + bias, + stats ========
// 128x128 tile, BK=32, 256 threads = 4 waves, each wave 64x64 (4x4 MFMA 16x16x32).

__global__ __launch_bounds__(256) void gemm_mfma(const us_t* __restrict__ A,
                                                 const us_t* __restrict__ Wt,
                                                 const float* __restrict__ bias,
                                                 us_t* __restrict__ C,
                                                 float* __restrict__ sums,
                                                 float* __restrict__ sumsq,
                                                 int M, int K, int N) {
    __shared__ us_t sA[128 * 32];
    __shared__ us_t sB[128 * 32];

    const int tid = threadIdx.x;
    const int lane = tid & 63;
    const int wave = tid >> 6;
    const int wm = wave >> 1;
    const int wn = wave & 1;
    const int bm = blockIdx.y * 128;
    const int bn = blockIdx.x * 128;

    f32x4 acc[4][4] = {};

    const int lrow = lane & 15;
    const int lquad = lane >> 4;

    for (int k0 = 0; k0 < K; k0 += 32) {
        // global loads to regs (2 chunks of the A tile + 2 of the B tile per thread)
        us8 ar[2], br[2];
        #pragma unroll
        for (int i = 0; i < 2; i++) {
            int id = tid + 256 * i;
            int row = id >> 2;
            int q = id & 3;
            ar[i] = *(const us8*)&A[(size_t)(bm + row) * K + k0 + q * 8];
            br[i] = *(const us8*)&Wt[(size_t)(bn + row) * K + k0 + q * 8];
        }
        __syncthreads();   // previous iteration's ds_reads done
        #pragma unroll
        for (int i = 0; i < 2; i++) {
            int id = tid + 256 * i;
            int row = id >> 2;
            int q = id & 3;
            *(us8*)&sA[row * 32 + q * 8] = ar[i];
            *(us8*)&sB[row * 32 + q * 8] = br[i];
        }
        __syncthreads();

        bf16x8 af[4], bf[4];
        #pragma unroll
        for (int i = 0; i < 4; i++) {
            af[i] = as_bf(*(const us8*)&sA[(wm * 64 + i * 16 + lrow) * 32 + lquad * 8]);
            bf[i] = as_bf(*(const us8*)&sB[(wn * 64 + i * 16 + lrow) * 32 + lquad * 8]);
        }
        #pragma unroll
        for (int i = 0; i < 4; i++)
            #pragma unroll
            for (int j = 0; j < 4; j++)
                acc[i][j] = __builtin_amdgcn_mfma_f32_16x16x32_bf16(af[i], bf[j], acc[i][j], 0, 0, 0);
    }

    // epilogue: bias, bf16 store (rows < M), fused column stats
    const int cb = bn + wn * 64 + lrow;
    const int rb = bm + wm * 64 + lquad * 4;
    #pragma unroll
    for (int j = 0; j < 4; j++) {
        int col = cb + j * 16;
        float bcol = bias[col];
        float cs = 0.f, cq = 0.f;
        #pragma unroll
        for (int i = 0; i < 4; i++) {
            #pragma unroll
            for (int r = 0; r < 4; r++) {
                int row = rb + i * 16 + r;
                float zv = acc[i][j][r] + bcol;
                if (row < M) {
                    C[(size_t)row * N + col] = f2b(zv);
                    cs += zv;
                    cq += zv * zv;
                }
            }
        }
        cs += __shfl_xor(cs, 16); cs += __shfl_xor(cs, 32);
        cq += __shfl_xor(cq, 16); cq += __shfl_xor(cq, 32);
        if (lquad == 0) {
            atomicAdd(&sums[col], cs);
            atomicAdd(&sumsq[col], cq);
        }
    }
}

// ================= BN finalize =================

__global__ void bn_finalize(const float* __restrict__ sums, const float* __restrict__ sumsq,
                            const float* __restrict__ g, const float* __restrict__ be,
                            float* __restrict__ s, float* __restrict__ t, int F, float invM) {
    int f = threadIdx.x;
    if (f < F) {
        float m = sums[f] * invM;
        float v = sumsq[f] * invM - m * m;
        float sc = g[f] * rsqrtf(v + BN_EPS);
        s[f] = sc;
        t[f] = be[f] - m * sc;
    }
}

// ================= BN apply + relu: z bf16 -> h bf16 =================

__global__ void bn_apply_bf(const us_t* __restrict__ z, const float* __restrict__ s,
                            const float* __restrict__ t, us_t* __restrict__ h,
                            int n4, int fq_mask) {
    int i = blockIdx.x * blockDim.x + threadIdx.x;
    if (i < n4) {
        int f0 = (i & fq_mask) * 4;
        float4 sv = *(const float4*)&s[f0];
        float4 tv = *(const float4*)&t[f0];
        us4 v = *(const us4*)&z[(size_t)i * 4];
        us4 o;
        o[0] = f2b(fmaxf(0.f, b2f(v[0]) * sv.x + tv.x));
        o[1] = f2b(fmaxf(0.f, b2f(v[1]) * sv.y + tv.y));
        o[2] = f2b(fmaxf(0.f, b2f(v[2]) * sv.z + tv.z));
        o[3] = f2b(fmaxf(0.f, b2f(v[3]) * sv.w + tv.w));
        *(us4*)&h[(size_t)i * 4] = o;
    }
}

// ================= pool (bf16 in, fused BN+relu, fp32 atomic out) =================

__global__ void pool_bn_bf(const us_t* __restrict__ z, const float* __restrict__ s,
                           const float* __restrict__ t, const int* __restrict__ batch,
                           float* __restrict__ hg) {
    int f = threadIdx.x;  // 256
    int n0 = blockIdx.x * 32;
    int n1 = min(n0 + 32, NNODES);
    float sv = s[f], tv = t[f];
    float acc = 0.f;
    int gc = batch[n0];
    for (int n = n0; n < n1; n++) {
        int g = batch[n];
        if (g != gc) {
            atomicAdd(&hg[gc * 256 + f], acc);
            acc = 0.f;
            gc = g;
        }
        acc += fmaxf(0.f, b2f(z[(size_t)n * 256 + f]) * sv + tv);
    }
    atomicAdd(&hg[gc * 256 + f], acc);
}

// ================= head GEMM fp32 (M=1000,K=256,N=128) + stats =================

#define GBM 128
#define GBN 128
#define GBK 16
#define LDA 132

__global__ __launch_bounds__(256) void gemm_f32_head(
    const float* __restrict__ A, const float* __restrict__ W, const float* __restrict__ bias,
    float* __restrict__ C, float* __restrict__ sums, float* __restrict__ sumsq,
    int M, int K, int N) {
    __shared__ float smem[2 * GBK * LDA];
    float* As = smem;
    float* Ws = smem + GBK * LDA;

    const int bm = blockIdx.y * GBM;
    const int bn = blockIdx.x * GBN;
    const int tid = threadIdx.x;
    const int tm = tid >> 4;
    const int tn = tid & 15;

    float acc[2][2][4][4] = {};

    for (int k0 = 0; k0 < K; k0 += GBK) {
        #pragma unroll
        for (int i = 0; i < 2; i++) {
            int id = tid + 256 * i;
            int row = id >> 2;
            int kq = id & 3;
            int gr = bm + row;
            int kk = k0 + kq * 4;
            float4 a4 = make_float4(0.f, 0.f, 0.f, 0.f);
            if (gr < M && kk < K) a4 = *(const float4*)&A[(size_t)gr * K + kk];
            As[(kq * 4 + 0) * LDA + row] = a4.x;
            As[(kq * 4 + 1) * LDA + row] = a4.y;
            As[(kq * 4 + 2) * LDA + row] = a4.z;
            As[(kq * 4 + 3) * LDA + row] = a4.w;
        }
        #pragma unroll
        for (int i = 0; i < 2; i++) {
            int id = tid + 256 * i;
            int kl = id >> 5;
            int c = id & 31;
            int kk = k0 + kl;
            float4 w4 = make_float4(0.f, 0.f, 0.f, 0.f);
            if (kk < K && bn + c * 4 < N) w4 = *(const float4*)&W[(size_t)kk * N + bn + c * 4];
            *(float4*)&Ws[kl * LDA + c * 4] = w4;
        }
        __syncthreads();
        #pragma unroll
        for (int k = 0; k < GBK; k++) {
            float4 a0 = *(float4*)&As[k * LDA + tm * 4];
            float4 a1 = *(float4*)&As[k * LDA + 64 + tm * 4];
            float4 w0 = *(float4*)&Ws[k * LDA + tn * 4];
            float4 w1 = *(float4*)&Ws[k * LDA + 64 + tn * 4];
            float ar[2][4] = {{a0.x, a0.y, a0.z, a0.w}, {a1.x, a1.y, a1.z, a1.w}};
            float wr[2][4] = {{w0.x, w0.y, w0.z, w0.w}, {w1.x, w1.y, w1.z, w1.w}};
            #pragma unroll
            for (int ri = 0; ri < 2; ri++)
                #pragma unroll
                for (int ci = 0; ci < 2; ci++)
                    #pragma unroll
                    for (int ii = 0; ii < 4; ii++)
                        #pragma unroll
                        for (int jj = 0; jj < 4; jj++)
                            acc[ri][ci][ii][jj] += ar[ri][ii] * wr[ci][jj];
        }
        __syncthreads();
    }

    float colsum[2][4] = {};
    float colsq[2][4] = {};
    #pragma unroll
    for (int ci = 0; ci < 2; ci++) {
        int colbase = bn + ci * 64 + tn * 4;
        if (colbase >= N) continue;
        float4 b4 = *(const float4*)&bias[colbase];
        float br[4] = {b4.x, b4.y, b4.z, b4.w};
        #pragma unroll
        for (int ri = 0; ri < 2; ri++) {
            #pragma unroll
            for (int ii = 0; ii < 4; ii++) {
                int row = bm + ri * 64 + tm * 4 + ii;
                if (row < M) {
                    float z0 = acc[ri][ci][ii][0] + br[0];
                    float z1 = acc[ri][ci][ii][1] + br[1];
                    float z2 = acc[ri][ci][ii][2] + br[2];
                    float z3 = acc[ri][ci][ii][3] + br[3];
                    *(float4*)&C[(size_t)row * N + colbase] = make_float4(z0, z1, z2, z3);
                    colsum[ci][0] += z0; colsq[ci][0] += z0 * z0;
                    colsum[ci][1] += z1; colsq[ci][1] += z1 * z1;
                    colsum[ci][2] += z2; colsq[ci][2] += z2 * z2;
                    colsum[ci][3] += z3; colsq[ci][3] += z3 * z3;
                }
            }
        }
    }
    __syncthreads();
    float* ps = smem;
    float* pq = smem + 2048;
    #pragma unroll
    for (int ci = 0; ci < 2; ci++)
        #pragma unroll
        for (int jj = 0; jj < 4; jj++) {
            int cl = ci * 64 + tn * 4 + jj;
            ps[tm * 128 + cl] = colsum[ci][jj];
            pq[tm * 128 + cl] = colsq[ci][jj];
        }
    __syncthreads();
    if (tid < 128 && bn + tid < N) {
        float s = 0.f, q = 0.f;
        #pragma unroll
        for (int i = 0; i < 16; i++) {
            s += ps[i * 128 + tid];
            q += pq[i * 128 + tid];
        }
        atomicAdd(&sums[bn + tid], s);
        atomicAdd(&sumsq[bn + tid], q);
    }
}

// ================= final head GEMV (BN+relu fused) =================

__global__ void final_gemv(const float* __restrict__ hg2, const float* __restrict__ s,
                           const float* __restrict__ t, const float* __restrict__ fw2,
                           const float* __restrict__ fb2, float* __restrict__ out) {
    int g = blockIdx.x;
    int l = threadIdx.x;  // 64
    float a0 = fmaxf(0.f, hg2[g * 128 + l] * s[l] + t[l]) * fw2[l];
    float a1 = fmaxf(0.f, hg2[g * 128 + 64 + l] * s[64 + l] + t[64 + l]) * fw2[64 + l];
    float v = a0 + a1;
    #pragma unroll
    for (int o = 32; o > 0; o >>= 1) v += __shfl_down(v, o);
    if (l == 0) out[g] = v + fb2[0];
}

// ================= launch =================

extern "C" void kernel_launch(void* const* d_in, const int* in_sizes, int n_in,
                              void* d_out, int out_size, void* d_ws, size_t ws_size,
                              hipStream_t stream) {
    const float* x = (const float*)d_in[0];
    const int* ei = (const int*)d_in[1];
    const int* batch = (const int*)d_in[2];
    const int* esrc = ei;
    const int* edst = ei + NEDGES;

    const float* l1w = (const float*)d_in[3],  *l1b = (const float*)d_in[4],
               * l1g = (const float*)d_in[5],  *l1be = (const float*)d_in[6];
    const float* l2w = (const float*)d_in[7],  *l2b = (const float*)d_in[8],
               * l2g = (const float*)d_in[9],  *l2be = (const float*)d_in[10];
    const float* l3w = (const float*)d_in[11], *l3b = (const float*)d_in[12],
               * l3g = (const float*)d_in[13], *l3be = (const float*)d_in[14];
    const float* l4w = (const float*)d_in[15], *l4b = (const float*)d_in[16],
               * l4g = (const float*)d_in[17], *l4be = (const float*)d_in[18];
    const float* l5w = (const float*)d_in[19], *l5b = (const float*)d_in[20],
               * l5g = (const float*)d_in[21], *l5be = (const float*)d_in[22];
    const float* l6w = (const float*)d_in[23], *l6b = (const float*)d_in[24],
               * l6g = (const float*)d_in[25], *l6be = (const float*)d_in[26];
    const float* fw1 = (const float*)d_in[27], *fb1 = (const float*)d_in[28],
               * fg  = (const float*)d_in[29], *fbe = (const float*)d_in[30];
    const float* fw2 = (const float*)d_in[31], *fb2 = (const float*)d_in[32];

    // ---- workspace carve ----
    us_t* bbuf0 = (us_t*)d_ws;                        // MPAD*256 bf16
    us_t* bbuf1 = bbuf0 + (size_t)MPAD * 256;
    us_t* bbuf2 = bbuf1 + (size_t)MPAD * 256;
    us_t* wt2 = bbuf2 + (size_t)MPAD * 256;           // [128][128]
    us_t* wt3 = wt2 + 128 * 128;                      // [256][128]
    us_t* wt4 = wt3 + 256 * 128;                      // [256][256]
    us_t* wt5 = wt4 + 256 * 256;
    us_t* wt6 = wt5 + 256 * 256;
    float* agg11 = (float*)(wt6 + 256 * 256);         // [50000][11]
    float* hg = agg11 + (size_t)NNODES * 11;          // [1000][256]
    float* hg2 = hg + NGRAPHS * 256;                  // [1000][128]
    float* stats = hg2 + NGRAPHS * 128;               // 7 x 1024
    int* deg = (int*)(stats + 7 * 1024);              // [50001]
    int* rowptr = deg + (NNODES + 1);
    int* cursor = rowptr + (NNODES + 1);
    int* chunkTot = cursor + (NNODES + 1);            // [64]
    int* tmpscan = chunkTot + 64;
    int* eidx = tmpscan + (NNODES + 1);               // [800000]

    // zero hg + hg2 + stats + deg (contiguous)
    {
        int zn = NGRAPHS * 256 + NGRAPHS * 128 + 7 * 1024 + (NNODES + 1);
        zero_f32<<<(zn + 255) / 256, 256, 0, stream>>>(hg, zn);
    }

    // CSR
    csr_hist<<<(NEDGES + 255) / 256, 256, 0, stream>>>(edst, deg, NEDGES);
    int nchunks = (NNODES + 1023) / 1024;
    csr_scan1<<<nchunks, 1024, 0, stream>>>(deg, tmpscan, chunkTot, NNODES);
    csr_scan2<<<1, 64, 0, stream>>>(chunkTot, nchunks);
    csr_scan3<<<(NNODES + 255) / 256, 256, 0, stream>>>(deg, tmpscan, chunkTot, rowptr,
                                                        cursor, NNODES);
    csr_fill<<<(NEDGES + 255) / 256, 256, 0, stream>>>(esrc, edst, cursor, eidx, NEDGES);

    // weight converts (bf16, transposed)
    wt_convert<<<(128 * 128 + 255) / 256, 256, 0, stream>>>(l2w, wt2, 128, 128);
    wt_convert<<<(128 * 256 + 255) / 256, 256, 0, stream>>>(l3w, wt3, 128, 256);
    wt_convert<<<(256 * 256 + 255) / 256, 256, 0, stream>>>(l4w, wt4, 256, 256);
    wt_convert<<<(256 * 256 + 255) / 256, 256, 0, stream>>>(l5w, wt5, 256, 256);
    wt_convert<<<(256 * 256 + 255) / 256, 256, 0, stream>>>(l6w, wt6, 256, 256);

    auto st = [&](int i) { return stats + i * 1024; };
    auto fin = [&](int i, const float* g, const float* be, int F, float invM) {
        bn_finalize<<<1, 256, 0, stream>>>(st(i), st(i) + 256, g, be, st(i) + 512,
                                           st(i) + 768, F, invM);
    };
    const float invN = 1.0f / (float)NNODES;
    const float invG = 1.0f / (float)NGRAPHS;

    // ---- conv1: agg(x) -> 11->128 -> BN -> relu -> 128->128 -> BN ----
    gin_gather11<<<(NNODES + 15) / 16, 256, 0, stream>>>(x, rowptr, eidx, agg11);
    gemm11<<<(NNODES + 63) / 64, 256, 0, stream>>>(agg11, l1w, l1b, bbuf0, st(0), st(0) + 256);
    fin(0, l1g, l1be, 128, invN);
    bn_apply_bf<<<(NNODES * 32 + 255) / 256, 256, 0, stream>>>(bbuf0, st(0) + 512, st(0) + 768,
                                                               bbuf1, NNODES * 32, 31);
    gemm_mfma<<<dim3(1, 391), 256, 0, stream>>>(bbuf1, wt2, l2b, bbuf0, st(1), st(1) + 256,
                                                NNODES, 128, 128);
    fin(1, l2g, l2be, 128, invN);

    // ---- conv2: gather(bnrelu z2) -> 128->256 -> BN -> relu -> 256->256 -> BN ----
    gin_gather_bf<128><<<(NNODES + 7) / 8, 256, 0, stream>>>(bbuf0, st(1) + 512, st(1) + 768,
                                                             rowptr, eidx, bbuf1);
    gemm_mfma<<<dim3(2, 391), 256, 0, stream>>>(bbuf1, wt3, l3b, bbuf2, st(2), st(2) + 256,
                                                NNODES, 128, 256);
    fin(2, l3g, l3be, 256, invN);
    bn_apply_bf<<<(NNODES * 64 + 255) / 256, 256, 0, stream>>>(bbuf2, st(2) + 512, st(2) + 768,
                                                               bbuf0, NNODES * 64, 63);
    gemm_mfma<<<dim3(2, 391), 256, 0, stream>>>(bbuf0, wt4, l4b, bbuf1, st(3), st(3) + 256,
                                                NNODES, 256, 256);
    fin(3, l4g, l4be, 256, invN);

    // ---- conv3 ----
    gin_gather_bf<256><<<(NNODES + 3) / 4, 256, 0, stream>>>(bbuf1, st(3) + 512, st(3) + 768,
                                                             rowptr, eidx, bbuf2);
    gemm_mfma<<<dim3(2, 391), 256, 0, stream>>>(bbuf2, wt5, l5b, bbuf0, st(4), st(4) + 256,
                                                NNODES, 256, 256);
    fin(4, l5g, l5be, 256, invN);
    bn_apply_bf<<<(NNODES * 64 + 255) / 256, 256, 0, stream>>>(bbuf0, st(4) + 512, st(4) + 768,
                                                               bbuf1, NNODES * 64, 63);
    gemm_mfma<<<dim3(2, 391), 256, 0, stream>>>(bbuf1, wt6, l6b, bbuf2, st(5), st(5) + 256,
                                                NNODES, 256, 256);
    fin(5, l6g, l6be, 256, invN);

    // ---- pool + head ----
    pool_bn_bf<<<(NNODES + 31) / 32, 256, 0, stream>>>(bbuf2, st(5) + 512, st(5) + 768,
                                                       batch, hg);
    gemm_f32_head<<<dim3(1, 8), 256, 0, stream>>>(hg, fw1, fb1, hg2, st(6), st(6) + 256,
                                                  NGRAPHS, 256, 128);
    fin(6, fg, fbe, 128, invG);
    final_gemv<<<NGRAPHS, 64, 0, stream>>>(hg2, st(6) + 512, st(6) + 768, fw2, fb2,
                                           (float*)d_out);
}